// Round 2
// baseline (736.344 us; speedup 1.0000x reference)
//
#include <hip/hip_runtime.h>
#include <hip/hip_bf16.h>

// GraphSAGE 2-layer, N=50000 nodes, d=128->32->32, E=800000 edges, fp32.
// Identity: segmean(x[src]) @ W == segmean((x@W)[src]) -> project to 32 dims
// BEFORE the edge scatter (4x less atomic traffic, L2-resident targets).
//
// NOTE: harness passes integer inputs as int32 (NOT int64) — edge_index is
// const int* with in_sizes[1] = 2*E elements. Round-1 crash was reading it
// as long long (OOB + garbage indices -> GPU memory fault).
//
// Memory plan (scratch-frugal, 13.0 MB of d_ws):
//   ws:   cnt [N], zc [N][64] (cols 0..31 = neighbor-proj, 32..63 = self-proj;
//                              reused in-place for layer 2 by k3)
//   d_out: doubles as agg1 then agg2 (memset -> scatter -> consume, in order)

#define N_NODES 50000
#define NPB 32  // nodes per block for the GEMM kernels

// ---- k1: zc[n][0:32) = x@W1l ; zc[n][32:64) = x@W1r ----------------------
__global__ __launch_bounds__(256) void k1_proj(
    const float* __restrict__ x, const float* __restrict__ W1l,
    const float* __restrict__ W1r, float* __restrict__ zc, int N) {
  __shared__ float xs[NPB * 128];
  const int block0 = blockIdx.x * NPB;
  const int t = threadIdx.x;
  {
    int maxn = N - block0;
    if (maxn > NPB) maxn = NPB;
    const float4* xg = (const float4*)(x + (size_t)block0 * 128);
    float4* xs4 = (float4*)xs;
    const int lim4 = maxn * 32;  // maxn*128/4
    for (int i = t; i < lim4; i += 256) xs4[i] = xg[i];
  }
  __syncthreads();
  const int wave = t >> 6, lane = t & 63, col = lane & 31;
  const float* Wp = (lane < 32) ? (W1l + col) : (W1r + col);
  float acc[8];
#pragma unroll
  for (int n = 0; n < 8; n++) acc[n] = 0.f;
  const int nbase = wave * 8;
#pragma unroll
  for (int kc = 0; kc < 4; kc++) {
    float w[32];
#pragma unroll
    for (int i = 0; i < 32; i++) w[i] = Wp[(kc * 32 + i) * 32];
#pragma unroll
    for (int n = 0; n < 8; n++) {
      const float4* xr = (const float4*)(xs + (nbase + n) * 128 + kc * 32);
#pragma unroll
      for (int i4 = 0; i4 < 8; i4++) {
        float4 xv = xr[i4];
        acc[n] += xv.x * w[i4 * 4 + 0] + xv.y * w[i4 * 4 + 1] +
                  xv.z * w[i4 * 4 + 2] + xv.w * w[i4 * 4 + 3];
      }
    }
  }
#pragma unroll
  for (int n = 0; n < 8; n++) {
    int node = block0 + nbase + n;
    if (node < N) zc[(size_t)node * 64 + lane] = acc[n];
  }
}

// ---- edge scatter: agg[dst][j] += zc[src][j], j in [0,32) ----------------
__global__ __launch_bounds__(256) void kscatter(
    const int* __restrict__ src, const int* __restrict__ dst,
    const float* __restrict__ zc, float* __restrict__ agg,
    float* __restrict__ cnt, int E) {
  int tid = blockIdx.x * 256 + threadIdx.x;
  int e = tid >> 5;
  int j = tid & 31;
  if (e < E) {
    int s = src[e];
    int d = dst[e];
    float v = zc[(size_t)s * 64 + j];
    unsafeAtomicAdd(&agg[(size_t)d * 32 + j], v);
    if (cnt != nullptr && j == 0) unsafeAtomicAdd(&cnt[d], 1.0f);
  }
}

// ---- k3: h = relu(agg1/max(cnt,1)+b1+self); zc <- [h@W2l | h@W2r] --------
// In-place on zc: each block reads/writes only its own 32-node slice, with a
// __syncthreads() between the read (to LDS) and the write.
__global__ __launch_bounds__(256) void k3_layer2(
    float* __restrict__ zc, const float* __restrict__ agg,
    const float* __restrict__ cnt, const float* __restrict__ b1,
    const float* __restrict__ W2l, const float* __restrict__ W2r, int N) {
  __shared__ float hs[NPB * 32];
  const int block0 = blockIdx.x * NPB;
  const int t = threadIdx.x;
  for (int i = t; i < NPB * 32; i += 256) {
    int n = i >> 5, c = i & 31;
    int node = block0 + n;
    float v = 0.f;
    if (node < N) {
      float ct = cnt[node];
      ct = ct < 1.f ? 1.f : ct;
      v = agg[(size_t)node * 32 + c] / ct + b1[c] +
          zc[(size_t)node * 64 + 32 + c];
      v = v > 0.f ? v : 0.f;
    }
    hs[i] = v;
  }
  __syncthreads();
  const int wave = t >> 6, lane = t & 63, col = lane & 31;
  const float* Wp = (lane < 32) ? (W2l + col) : (W2r + col);
  float w[32];
#pragma unroll
  for (int i = 0; i < 32; i++) w[i] = Wp[i * 32];
  const int nbase = wave * 8;
#pragma unroll
  for (int n = 0; n < 8; n++) {
    const float4* hr = (const float4*)(hs + (nbase + n) * 32);
    float acc = 0.f;
#pragma unroll
    for (int i4 = 0; i4 < 8; i4++) {
      float4 hv = hr[i4];
      acc += hv.x * w[i4 * 4 + 0] + hv.y * w[i4 * 4 + 1] +
             hv.z * w[i4 * 4 + 2] + hv.w * w[i4 * 4 + 3];
    }
    int node = block0 + nbase + n;
    if (node < N) zc[(size_t)node * 64 + lane] = acc;
  }
}

// ---- k5: out = out/max(cnt,1) + b2 + self2 (in-place on d_out) -----------
__global__ __launch_bounds__(256) void k5_epilogue(
    const float* __restrict__ zc, const float* __restrict__ cnt,
    const float* __restrict__ b2, float* __restrict__ out, int N) {
  int i = blockIdx.x * 256 + threadIdx.x;
  if (i < N * 32) {
    int n = i >> 5, c = i & 31;
    float ct = cnt[n];
    ct = ct < 1.f ? 1.f : ct;
    out[i] = out[i] / ct + b2[c] + zc[(size_t)n * 64 + 32 + c];
  }
}

extern "C" void kernel_launch(void* const* d_in, const int* in_sizes, int n_in,
                              void* d_out, int out_size, void* d_ws,
                              size_t ws_size, hipStream_t stream) {
  const float* x = (const float*)d_in[0];
  const int* ei = (const int*)d_in[1];  // int32! (harness narrows int64)
  const float* W1l = (const float*)d_in[2];
  const float* b1 = (const float*)d_in[3];
  const float* W1r = (const float*)d_in[4];
  const float* W2l = (const float*)d_in[5];
  const float* b2 = (const float*)d_in[6];
  const float* W2r = (const float*)d_in[7];
  float* out = (float*)d_out;

  const int N = N_NODES;
  const int E = in_sizes[1] / 2;  // 800000

  float* ws = (float*)d_ws;
  float* cnt = ws;        // N floats
  float* zc = ws + N;     // N*64 floats (N*4 bytes offset keeps 16B align)

  hipMemsetAsync(cnt, 0, (size_t)N * sizeof(float), stream);
  hipMemsetAsync(out, 0, (size_t)N * 32 * sizeof(float), stream);

  const int* srcp = ei;
  const int* dstp = ei + E;
  const int nblk_gemm = (N + NPB - 1) / NPB;
  const int nblk_scat = (E * 32 + 255) / 256;  // 25.6M threads

  k1_proj<<<nblk_gemm, 256, 0, stream>>>(x, W1l, W1r, zc, N);
  kscatter<<<nblk_scat, 256, 0, stream>>>(srcp, dstp, zc, out, cnt, E);
  k3_layer2<<<nblk_gemm, 256, 0, stream>>>(zc, out, cnt, b1, W2l, W2r, N);
  hipMemsetAsync(out, 0, (size_t)N * 32 * sizeof(float), stream);
  kscatter<<<nblk_scat, 256, 0, stream>>>(srcp, dstp, zc, out, nullptr, E);
  k5_epilogue<<<(N * 32 + 255) / 256, 256, 0, stream>>>(zc, cnt, b2, out, N);
}

// Round 3
// 676.863 us; speedup vs baseline: 1.0879x; 1.0879x over previous
//
#include <hip/hip_runtime.h>
#include <hip/hip_bf16.h>

// GraphSAGE 2-layer, N=50000, d=128->32->32, E=800000, fp32.
//
// R2 post-mortem: atomic scatter was the bottleneck (847 MB WRITE_SIZE from
// cross-XCD atomic-RMW line ping-pong, ~430us/dispatch). R3: build CSR by dst
// once (hist -> scan -> fill), then aggregate as a deterministic gather-sum
// (half-wave per node, 32 lanes = 32 features) with ZERO feature atomics.
// Mean/bias/self/ReLU fused into the aggregation kernels.
//
// Identity retained: segmean(x[src]) @ W == segmean((x@W)[src]) -> project to
// 32+32 dims before any edge traversal.
//
// ws layout: zc[N][64] | adj[E] | row_ptr[N+1] | wptr[N] | cnt_i[N]  (~16.6MB)
// d_out doubles as h[N][32] between k_agg(L1) and k2_proj (overwritten later).

#define N_NODES 50000
#define NPB 32  // nodes per block in the projection GEMMs

// ---- k1: zc[n][0:32) = x@W1l ; zc[n][32:64) = x@W1r ----------------------
__global__ __launch_bounds__(256) void k1_proj(
    const float* __restrict__ x, const float* __restrict__ W1l,
    const float* __restrict__ W1r, float* __restrict__ zc, int N) {
  __shared__ float xs[NPB * 128];
  const int block0 = blockIdx.x * NPB;
  const int t = threadIdx.x;
  {
    int maxn = N - block0;
    if (maxn > NPB) maxn = NPB;
    const float4* xg = (const float4*)(x + (size_t)block0 * 128);
    float4* xs4 = (float4*)xs;
    const int lim4 = maxn * 32;
    for (int i = t; i < lim4; i += 256) xs4[i] = xg[i];
  }
  __syncthreads();
  const int wave = t >> 6, lane = t & 63, col = lane & 31;
  const float* Wp = (lane < 32) ? (W1l + col) : (W1r + col);
  float acc[8];
#pragma unroll
  for (int n = 0; n < 8; n++) acc[n] = 0.f;
  const int nbase = wave * 8;
#pragma unroll
  for (int kc = 0; kc < 4; kc++) {
    float w[32];
#pragma unroll
    for (int i = 0; i < 32; i++) w[i] = Wp[(kc * 32 + i) * 32];
#pragma unroll
    for (int n = 0; n < 8; n++) {
      const float4* xr = (const float4*)(xs + (nbase + n) * 128 + kc * 32);
#pragma unroll
      for (int i4 = 0; i4 < 8; i4++) {
        float4 xv = xr[i4];
        acc[n] += xv.x * w[i4 * 4 + 0] + xv.y * w[i4 * 4 + 1] +
                  xv.z * w[i4 * 4 + 2] + xv.w * w[i4 * 4 + 3];
      }
    }
  }
#pragma unroll
  for (int n = 0; n < 8; n++) {
    int node = block0 + nbase + n;
    if (node < N) zc[(size_t)node * 64 + lane] = acc[n];
  }
}

// ---- CSR build: histogram of dst ----------------------------------------
__global__ __launch_bounds__(256) void k_hist(const int* __restrict__ dst,
                                              int* __restrict__ cnt, int E) {
  int e = blockIdx.x * 256 + threadIdx.x;
  if (e < E) atomicAdd(&cnt[dst[e]], 1);
}

// ---- CSR build: exclusive scan over cnt -> row_ptr, wptr -----------------
// Block b: base = sum(cnt[0 .. b*256)) via strided reduce (L2-resident),
// then Hillis-Steele scan of its own 256 values.
__global__ __launch_bounds__(256) void k_scan(const int* __restrict__ cnt,
                                              int* __restrict__ row_ptr,
                                              int* __restrict__ wptr, int N) {
  __shared__ int lds[256];
  __shared__ int wsum[4];
  __shared__ int base_s;
  const int b = blockIdx.x, t = threadIdx.x;
  const int start = b * 256;
  int part = 0;
  for (int i = t; i < start; i += 256) part += cnt[i];
#pragma unroll
  for (int off = 32; off >= 1; off >>= 1) part += __shfl_down(part, off, 64);
  if ((t & 63) == 0) wsum[t >> 6] = part;
  __syncthreads();
  if (t == 0) base_s = wsum[0] + wsum[1] + wsum[2] + wsum[3];
  __syncthreads();
  const int base = base_s;
  const int i = start + t;
  const int v = (i < N) ? cnt[i] : 0;
  lds[t] = v;
  __syncthreads();
  for (int off = 1; off < 256; off <<= 1) {
    int tmp = (t >= off) ? lds[t - off] : 0;
    __syncthreads();
    lds[t] += tmp;
    __syncthreads();
  }
  if (i < N) {
    int excl = base + lds[t] - v;
    row_ptr[i] = excl;
    wptr[i] = excl;
    if (i == N - 1) row_ptr[N] = base + lds[t];
  }
}

// ---- CSR build: fill adjacency (src list sorted by dst) ------------------
__global__ __launch_bounds__(256) void k_fill(const int* __restrict__ src,
                                              const int* __restrict__ dst,
                                              int* __restrict__ wptr,
                                              int* __restrict__ adj, int E) {
  int e = blockIdx.x * 256 + threadIdx.x;
  if (e < E) {
    int d = dst[e];
    int pos = atomicAdd(&wptr[d], 1);
    adj[pos] = src[e];
  }
}

// ---- aggregation: out[n][j] = f(mean_nbr(zc[:,j]) + bias[j] + zc[n][32+j])
// Half-wave (32 lanes) per node; deterministic gather-sum, no atomics.
__global__ __launch_bounds__(256) void k_agg(
    const float* __restrict__ zc, const int* __restrict__ adj,
    const int* __restrict__ row_ptr, const float* __restrict__ bias,
    float* __restrict__ out, int N, int do_relu) {
  const int t = threadIdx.x;
  const int j = t & 31;
  const int node = blockIdx.x * 8 + (t >> 5);
  if (node >= N) return;
  const int r0 = row_ptr[node], r1 = row_ptr[node + 1];
  float a0 = 0.f, a1 = 0.f, a2 = 0.f, a3 = 0.f;
  int e = r0;
  for (; e + 4 <= r1; e += 4) {
    int s0 = adj[e], s1 = adj[e + 1], s2 = adj[e + 2], s3 = adj[e + 3];
    a0 += zc[(size_t)s0 * 64 + j];
    a1 += zc[(size_t)s1 * 64 + j];
    a2 += zc[(size_t)s2 * 64 + j];
    a3 += zc[(size_t)s3 * 64 + j];
  }
  for (; e < r1; ++e) a0 += zc[(size_t)adj[e] * 64 + j];
  float sum = (a0 + a1) + (a2 + a3);
  const int deg = r1 - r0;
  float m = sum / (float)(deg > 1 ? deg : 1);
  float v = m + bias[j] + zc[(size_t)node * 64 + 32 + j];
  out[(size_t)node * 32 + j] = do_relu ? fmaxf(v, 0.f) : v;
}

// ---- k2: zc[n][0:32) = h@W2l ; zc[n][32:64) = h@W2r (h read from global) -
__global__ __launch_bounds__(256) void k2_proj(
    const float* __restrict__ h, const float* __restrict__ W2l,
    const float* __restrict__ W2r, float* __restrict__ zc, int N) {
  __shared__ float hs[NPB * 32];
  const int block0 = blockIdx.x * NPB;
  const int t = threadIdx.x;
  {
    int maxn = N - block0;
    if (maxn > NPB) maxn = NPB;
    const int lim = maxn * 32;
    const float* hg = h + (size_t)block0 * 32;
    for (int i = t; i < lim; i += 256) hs[i] = hg[i];
  }
  __syncthreads();
  const int wave = t >> 6, lane = t & 63, col = lane & 31;
  const float* Wp = (lane < 32) ? (W2l + col) : (W2r + col);
  float w[32];
#pragma unroll
  for (int i = 0; i < 32; i++) w[i] = Wp[i * 32];
  const int nbase = wave * 8;
#pragma unroll
  for (int n = 0; n < 8; n++) {
    const float4* hr = (const float4*)(hs + (nbase + n) * 32);
    float acc = 0.f;
#pragma unroll
    for (int i4 = 0; i4 < 8; i4++) {
      float4 hv = hr[i4];
      acc += hv.x * w[i4 * 4 + 0] + hv.y * w[i4 * 4 + 1] +
             hv.z * w[i4 * 4 + 2] + hv.w * w[i4 * 4 + 3];
    }
    int node = block0 + nbase + n;
    if (node < N) zc[(size_t)node * 64 + lane] = acc;
  }
}

extern "C" void kernel_launch(void* const* d_in, const int* in_sizes, int n_in,
                              void* d_out, int out_size, void* d_ws,
                              size_t ws_size, hipStream_t stream) {
  const float* x = (const float*)d_in[0];
  const int* ei = (const int*)d_in[1];  // int32 (harness narrows int64)
  const float* W1l = (const float*)d_in[2];
  const float* b1 = (const float*)d_in[3];
  const float* W1r = (const float*)d_in[4];
  const float* W2l = (const float*)d_in[5];
  const float* b2 = (const float*)d_in[6];
  const float* W2r = (const float*)d_in[7];
  float* out = (float*)d_out;

  const int N = N_NODES;
  const int E = in_sizes[1] / 2;  // 800000

  float* zc = (float*)d_ws;                  // N*64 floats
  int* adj = (int*)(zc + (size_t)N * 64);    // E
  int* row_ptr = adj + E;                    // N+1
  int* wptr = row_ptr + N + 1;               // N
  int* cnt_i = wptr + N;                     // N
  float* h = out;  // reuse d_out as h[N][32]; overwritten by final k_agg

  const int* srcp = ei;
  const int* dstp = ei + E;

  hipMemsetAsync(cnt_i, 0, (size_t)N * sizeof(int), stream);

  const int nblk_edge = (E + 255) / 256;            // 3125
  const int nblk_scan = (N + 255) / 256;            // 196
  const int nblk_gemm = (N + NPB - 1) / NPB;        // 1563
  const int nblk_agg = (N + 7) / 8;                 // 6250

  k_hist<<<nblk_edge, 256, 0, stream>>>(dstp, cnt_i, E);
  k_scan<<<nblk_scan, 256, 0, stream>>>(cnt_i, row_ptr, wptr, N);
  k_fill<<<nblk_edge, 256, 0, stream>>>(srcp, dstp, wptr, adj, E);

  k1_proj<<<nblk_gemm, 256, 0, stream>>>(x, W1l, W1r, zc, N);
  k_agg<<<nblk_agg, 256, 0, stream>>>(zc, adj, row_ptr, b1, h, N, 1);
  k2_proj<<<nblk_gemm, 256, 0, stream>>>(h, W2l, W2r, zc, N);
  k_agg<<<nblk_agg, 256, 0, stream>>>(zc, adj, row_ptr, b2, out, N, 0);
}

// Round 4
// 277.310 us; speedup vs baseline: 2.6553x; 2.4408x over previous
//
#include <hip/hip_runtime.h>
#include <hip/hip_bf16.h>

// GraphSAGE 2-layer, N=50000, d=128->32->32, E=800000, fp32.
//
// R3 post-mortem: the 430us/845MB-write dispatch WAS k1_proj — VGPR_Count=256
// + deterministic 845MB writes = register SPILL to scratch (w[32] per-lane
// array under 4x-unrolled kc loop). R4: projection rewritten as LDS-tiled
// GEMM, 64 nodes x 64 cols per block, 4x4 micro-tile per thread, weights in
// LDS (broadcast reads), acc[4][4] in regs -> ~50 VGPRs, no spill.
//
// Aggregation stays CSR gather-sum (R3): hist -> scan -> fill, then
// deterministic per-node reduction, zero feature atomics.
//
// ws layout: zc[N][64] | adj[E] | row_ptr[N+1] | wptr[N] | cnt_i[N]  (~16.6MB)
// d_out doubles as h[N][32] between k_agg(L1) and kproj(L2).

#define N_NODES 50000

// ---- unified projection: z[n][0:32)=in@Wl, z[n][32:64)=in@Wr -------------
// in: [N][K] (K=128 or 32), Wl/Wr: [K][32]. Block: 256 thr = 64 nodes x 64
// cols, thread = 4 nodes x 4 cols. K processed in chunks of <=64.
// LDS: xs[64][68] (pad: 4*68=272 = 16 mod 32 -> 2-way, free) + ws[64][64].
__global__ __launch_bounds__(256) void kproj(
    const float* __restrict__ in, const float* __restrict__ Wl,
    const float* __restrict__ Wr, float* __restrict__ z, int N, int K) {
  __shared__ float xs[64 * 68];
  __shared__ float ws[64 * 64];
  const int t = threadIdx.x;
  const int n0 = blockIdx.x * 64;
  const int nvalid = (N - n0) < 64 ? (N - n0) : 64;

  const int tx = t & 15, ty = t >> 4;
  const int c0 = tx * 4;   // output col 0..63
  const int nl = ty * 4;   // local node 0..63

  float acc[4][4];
#pragma unroll
  for (int i = 0; i < 4; i++)
#pragma unroll
    for (int j = 0; j < 4; j++) acc[i][j] = 0.f;

  for (int kc = 0; kc < K; kc += 64) {
    const int KC = (K - kc) < 64 ? (K - kc) : 64;  // 64 or 32
    // stage W chunk: ws[k][c] (c<32: Wl, else Wr), coalesced, 2-way free
    for (int i = t; i < KC * 32; i += 256) {
      int k = i >> 5, c = i & 31;
      ws[k * 64 + c] = Wl[(size_t)(kc + k) * 32 + c];
      ws[k * 64 + 32 + c] = Wr[(size_t)(kc + k) * 32 + c];
    }
    // stage x chunk: xs[n][k], float4 loads, guarded rows
    {
      const int kq = KC >> 2;  // float4 per row: 16 or 8
      const int sh = (KC == 64) ? 4 : 3;
      const int lim = nvalid * kq;
      for (int i = t; i < lim; i += 256) {
        int n = i >> sh, q = i & (kq - 1);
        float4 v = *(const float4*)(in + (size_t)(n0 + n) * K + kc + q * 4);
        *(float4*)(xs + n * 68 + q * 4) = v;
      }
    }
    __syncthreads();

    const float* x0 = xs + (nl + 0) * 68;
    const float* x1 = xs + (nl + 1) * 68;
    const float* x2 = xs + (nl + 2) * 68;
    const float* x3 = xs + (nl + 3) * 68;
    for (int k = 0; k < KC; k += 4) {
      float4 xa = *(const float4*)(x0 + k);
      float4 xb = *(const float4*)(x1 + k);
      float4 xc = *(const float4*)(x2 + k);
      float4 xd = *(const float4*)(x3 + k);
#pragma unroll
      for (int kk = 0; kk < 4; kk++) {
        float4 w = *(const float4*)(ws + (k + kk) * 64 + c0);
        float va = ((const float*)&xa)[kk];
        float vb = ((const float*)&xb)[kk];
        float vc = ((const float*)&xc)[kk];
        float vd = ((const float*)&xd)[kk];
        acc[0][0] += va * w.x; acc[0][1] += va * w.y;
        acc[0][2] += va * w.z; acc[0][3] += va * w.w;
        acc[1][0] += vb * w.x; acc[1][1] += vb * w.y;
        acc[1][2] += vb * w.z; acc[1][3] += vb * w.w;
        acc[2][0] += vc * w.x; acc[2][1] += vc * w.y;
        acc[2][2] += vc * w.z; acc[2][3] += vc * w.w;
        acc[3][0] += vd * w.x; acc[3][1] += vd * w.y;
        acc[3][2] += vd * w.z; acc[3][3] += vd * w.w;
      }
    }
    __syncthreads();
  }
#pragma unroll
  for (int i = 0; i < 4; i++) {
    int node = n0 + nl + i;
    if (node < N) {
      float4 v = make_float4(acc[i][0], acc[i][1], acc[i][2], acc[i][3]);
      *(float4*)(z + (size_t)node * 64 + c0) = v;
    }
  }
}

// ---- CSR build: histogram of dst ----------------------------------------
__global__ __launch_bounds__(256) void k_hist(const int* __restrict__ dst,
                                              int* __restrict__ cnt, int E) {
  int e = blockIdx.x * 256 + threadIdx.x;
  if (e < E) atomicAdd(&cnt[dst[e]], 1);
}

// ---- CSR build: exclusive scan over cnt -> row_ptr, wptr -----------------
__global__ __launch_bounds__(256) void k_scan(const int* __restrict__ cnt,
                                              int* __restrict__ row_ptr,
                                              int* __restrict__ wptr, int N) {
  __shared__ int lds[256];
  __shared__ int wsum[4];
  __shared__ int base_s;
  const int b = blockIdx.x, t = threadIdx.x;
  const int start = b * 256;
  int part = 0;
  for (int i = t; i < start; i += 256) part += cnt[i];
#pragma unroll
  for (int off = 32; off >= 1; off >>= 1) part += __shfl_down(part, off, 64);
  if ((t & 63) == 0) wsum[t >> 6] = part;
  __syncthreads();
  if (t == 0) base_s = wsum[0] + wsum[1] + wsum[2] + wsum[3];
  __syncthreads();
  const int base = base_s;
  const int i = start + t;
  const int v = (i < N) ? cnt[i] : 0;
  lds[t] = v;
  __syncthreads();
  for (int off = 1; off < 256; off <<= 1) {
    int tmp = (t >= off) ? lds[t - off] : 0;
    __syncthreads();
    lds[t] += tmp;
    __syncthreads();
  }
  if (i < N) {
    int excl = base + lds[t] - v;
    row_ptr[i] = excl;
    wptr[i] = excl;
    if (i == N - 1) row_ptr[N] = base + lds[t];
  }
}

// ---- CSR build: fill adjacency (src list grouped by dst) -----------------
__global__ __launch_bounds__(256) void k_fill(const int* __restrict__ src,
                                              const int* __restrict__ dst,
                                              int* __restrict__ wptr,
                                              int* __restrict__ adj, int E) {
  int e = blockIdx.x * 256 + threadIdx.x;
  if (e < E) {
    int d = dst[e];
    int pos = atomicAdd(&wptr[d], 1);
    adj[pos] = src[e];
  }
}

// ---- aggregation: out[n][j] = f(mean_nbr(zc[:,j]) + bias[j] + zc[n][32+j])
// Half-wave (32 lanes) per node; deterministic gather-sum, no atomics.
__global__ __launch_bounds__(256) void k_agg(
    const float* __restrict__ zc, const int* __restrict__ adj,
    const int* __restrict__ row_ptr, const float* __restrict__ bias,
    float* __restrict__ out, int N, int do_relu) {
  const int t = threadIdx.x;
  const int j = t & 31;
  const int node = blockIdx.x * 8 + (t >> 5);
  if (node >= N) return;
  const int r0 = row_ptr[node], r1 = row_ptr[node + 1];
  float a0 = 0.f, a1 = 0.f, a2 = 0.f, a3 = 0.f;
  int e = r0;
  for (; e + 4 <= r1; e += 4) {
    int s0 = adj[e], s1 = adj[e + 1], s2 = adj[e + 2], s3 = adj[e + 3];
    a0 += zc[(size_t)s0 * 64 + j];
    a1 += zc[(size_t)s1 * 64 + j];
    a2 += zc[(size_t)s2 * 64 + j];
    a3 += zc[(size_t)s3 * 64 + j];
  }
  for (; e < r1; ++e) a0 += zc[(size_t)adj[e] * 64 + j];
  float sum = (a0 + a1) + (a2 + a3);
  const int deg = r1 - r0;
  float m = sum / (float)(deg > 1 ? deg : 1);
  float v = m + bias[j] + zc[(size_t)node * 64 + 32 + j];
  out[(size_t)node * 32 + j] = do_relu ? fmaxf(v, 0.f) : v;
}

extern "C" void kernel_launch(void* const* d_in, const int* in_sizes, int n_in,
                              void* d_out, int out_size, void* d_ws,
                              size_t ws_size, hipStream_t stream) {
  const float* x = (const float*)d_in[0];
  const int* ei = (const int*)d_in[1];  // int32 (harness narrows int64)
  const float* W1l = (const float*)d_in[2];
  const float* b1 = (const float*)d_in[3];
  const float* W1r = (const float*)d_in[4];
  const float* W2l = (const float*)d_in[5];
  const float* b2 = (const float*)d_in[6];
  const float* W2r = (const float*)d_in[7];
  float* out = (float*)d_out;

  const int N = N_NODES;
  const int E = in_sizes[1] / 2;  // 800000

  float* zc = (float*)d_ws;                  // N*64 floats
  int* adj = (int*)(zc + (size_t)N * 64);    // E
  int* row_ptr = adj + E;                    // N+1
  int* wptr = row_ptr + N + 1;               // N
  int* cnt_i = wptr + N;                     // N
  float* h = out;  // reuse d_out as h[N][32]; overwritten by final k_agg

  const int* srcp = ei;
  const int* dstp = ei + E;

  hipMemsetAsync(cnt_i, 0, (size_t)N * sizeof(int), stream);

  const int nblk_edge = (E + 255) / 256;  // 3125
  const int nblk_scan = (N + 255) / 256;  // 196
  const int nblk_proj = (N + 63) / 64;    // 782
  const int nblk_agg = (N + 7) / 8;       // 6250

  k_hist<<<nblk_edge, 256, 0, stream>>>(dstp, cnt_i, E);
  k_scan<<<nblk_scan, 256, 0, stream>>>(cnt_i, row_ptr, wptr, N);
  k_fill<<<nblk_edge, 256, 0, stream>>>(srcp, dstp, wptr, adj, E);

  kproj<<<nblk_proj, 256, 0, stream>>>(x, W1l, W1r, zc, N, 128);
  k_agg<<<nblk_agg, 256, 0, stream>>>(zc, adj, row_ptr, b1, h, N, 1);
  kproj<<<nblk_proj, 256, 0, stream>>>(h, W2l, W2r, zc, N, 32);
  k_agg<<<nblk_agg, 256, 0, stream>>>(zc, adj, row_ptr, b2, out, N, 0);
}

// Round 5
// 188.080 us; speedup vs baseline: 3.9150x; 1.4744x over previous
//
#include <hip/hip_runtime.h>
#include <hip/hip_bf16.h>

// GraphSAGE 2-layer, N=50000, d=128->32->32, E=800000, fp32.
//
// R4 post-mortem: CSR build (k_hist + k_fill) = ~90us of 277us; WRITE_SIZE
// 51.8MB = 800k x 64B — every global atomicAdd dirties a full line at the
// memory-side coherence point (~60ns/edge, VALUBusy 0.4%). R5: replace with a
// two-level LDS counting sort (196 coarse buckets of 256 dst each):
//   k_bcount  : per-block LDS histogram -> blkhist[256][196] (no atomics)
//   k_bscan   : column running-sums (in-place) + bucket bases bb[] (1 block)
//   k_bscatter: LDS cursors -> ebuf[pos] = (src<<8)|(dst&255), grouped by bkt
//   k_bsort   : per-bucket LDS count+scan -> row_ptr + final adj (coalesced)
// Zero memory-side atomics; ~32MB of mostly-coalesced traffic.
//
// Projection (R4's LDS-tiled GEMM) and CSR gather-sum k_agg unchanged.
// ws: zc[N*64] | ebuf[E] | adj[E] | row_ptr[N+1] | bb[NB+1] | blkhist[G*NB]
// (~19.6MB). d_out doubles as h[N][32] between k_agg(L1) and kproj(L2).

#define N_NODES 50000
#define NB 196   // coarse buckets = ceil(N/256)
#define GB 256   // blocks in the bucket-count/scatter phases

// ---- unified projection: z[n][0:32)=in@Wl, z[n][32:64)=in@Wr -------------
__global__ __launch_bounds__(256) void kproj(
    const float* __restrict__ in, const float* __restrict__ Wl,
    const float* __restrict__ Wr, float* __restrict__ z, int N, int K) {
  __shared__ float xs[64 * 68];
  __shared__ float ws[64 * 64];
  const int t = threadIdx.x;
  const int n0 = blockIdx.x * 64;
  const int nvalid = (N - n0) < 64 ? (N - n0) : 64;

  const int tx = t & 15, ty = t >> 4;
  const int c0 = tx * 4;
  const int nl = ty * 4;

  float acc[4][4];
#pragma unroll
  for (int i = 0; i < 4; i++)
#pragma unroll
    for (int j = 0; j < 4; j++) acc[i][j] = 0.f;

  for (int kc = 0; kc < K; kc += 64) {
    const int KC = (K - kc) < 64 ? (K - kc) : 64;
    for (int i = t; i < KC * 32; i += 256) {
      int k = i >> 5, c = i & 31;
      ws[k * 64 + c] = Wl[(size_t)(kc + k) * 32 + c];
      ws[k * 64 + 32 + c] = Wr[(size_t)(kc + k) * 32 + c];
    }
    {
      const int kq = KC >> 2;
      const int sh = (KC == 64) ? 4 : 3;
      const int lim = nvalid * kq;
      for (int i = t; i < lim; i += 256) {
        int n = i >> sh, q = i & (kq - 1);
        float4 v = *(const float4*)(in + (size_t)(n0 + n) * K + kc + q * 4);
        *(float4*)(xs + n * 68 + q * 4) = v;
      }
    }
    __syncthreads();

    const float* x0 = xs + (nl + 0) * 68;
    const float* x1 = xs + (nl + 1) * 68;
    const float* x2 = xs + (nl + 2) * 68;
    const float* x3 = xs + (nl + 3) * 68;
    for (int k = 0; k < KC; k += 4) {
      float4 xa = *(const float4*)(x0 + k);
      float4 xb = *(const float4*)(x1 + k);
      float4 xc = *(const float4*)(x2 + k);
      float4 xd = *(const float4*)(x3 + k);
#pragma unroll
      for (int kk = 0; kk < 4; kk++) {
        float4 w = *(const float4*)(ws + (k + kk) * 64 + c0);
        float va = ((const float*)&xa)[kk];
        float vb = ((const float*)&xb)[kk];
        float vc = ((const float*)&xc)[kk];
        float vd = ((const float*)&xd)[kk];
        acc[0][0] += va * w.x; acc[0][1] += va * w.y;
        acc[0][2] += va * w.z; acc[0][3] += va * w.w;
        acc[1][0] += vb * w.x; acc[1][1] += vb * w.y;
        acc[1][2] += vb * w.z; acc[1][3] += vb * w.w;
        acc[2][0] += vc * w.x; acc[2][1] += vc * w.y;
        acc[2][2] += vc * w.z; acc[2][3] += vc * w.w;
        acc[3][0] += vd * w.x; acc[3][1] += vd * w.y;
        acc[3][2] += vd * w.z; acc[3][3] += vd * w.w;
      }
    }
    __syncthreads();
  }
#pragma unroll
  for (int i = 0; i < 4; i++) {
    int node = n0 + nl + i;
    if (node < N) {
      float4 v = make_float4(acc[i][0], acc[i][1], acc[i][2], acc[i][3]);
      *(float4*)(z + (size_t)node * 64 + c0) = v;
    }
  }
}

// ---- phase A: per-block LDS histogram of coarse buckets ------------------
__global__ __launch_bounds__(256) void k_bcount(const int* __restrict__ dst,
                                                int* __restrict__ blkhist,
                                                int E, int chunk) {
  __shared__ int h[NB];
  const int t = threadIdx.x, b = blockIdx.x;
  if (t < NB) h[t] = 0;
  __syncthreads();
  const int e0 = b * chunk;
  int e1 = e0 + chunk;
  if (e1 > E) e1 = E;
  for (int e = e0 + t; e < e1; e += 256) atomicAdd(&h[dst[e] >> 8], 1);
  __syncthreads();
  if (t < NB) blkhist[b * NB + t] = h[t];
}

// ---- phase B: column running sums (in-place) + bucket bases --------------
__global__ __launch_bounds__(256) void k_bscan(int* __restrict__ blkhist,
                                               int* __restrict__ bb, int E) {
  __shared__ int sc[256];
  const int t = threadIdx.x;
  int run = 0;
  if (t < NB) {
    for (int b = 0; b < GB; b += 8) {
      int v[8];
#pragma unroll
      for (int i = 0; i < 8; i++) v[i] = blkhist[(b + i) * NB + t];
#pragma unroll
      for (int i = 0; i < 8; i++) {
        blkhist[(b + i) * NB + t] = run;
        run += v[i];
      }
    }
  }
  sc[t] = (t < NB) ? run : 0;
  __syncthreads();
  for (int off = 1; off < 256; off <<= 1) {
    int tmp = (t >= off) ? sc[t - off] : 0;
    __syncthreads();
    sc[t] += tmp;
    __syncthreads();
  }
  if (t < NB) bb[t] = sc[t] - run;  // exclusive
  if (t == 0) bb[NB] = E;
}

// ---- phase C: scatter edges into coarse-bucket-grouped ebuf --------------
__global__ __launch_bounds__(256) void k_bscatter(
    const int* __restrict__ src, const int* __restrict__ dst,
    const int* __restrict__ blkhist, const int* __restrict__ bb,
    int* __restrict__ ebuf, int E, int chunk) {
  __shared__ int cur[NB];
  const int t = threadIdx.x, b = blockIdx.x;
  if (t < NB) cur[t] = bb[t] + blkhist[b * NB + t];
  __syncthreads();
  const int e0 = b * chunk;
  int e1 = e0 + chunk;
  if (e1 > E) e1 = E;
  for (int e = e0 + t; e < e1; e += 256) {
    int d = dst[e], s = src[e];
    int pos = atomicAdd(&cur[d >> 8], 1);
    ebuf[pos] = (s << 8) | (d & 255);
  }
}

// ---- phase D: per-bucket fine sort -> row_ptr + adj ----------------------
__global__ __launch_bounds__(256) void k_bsort(const int* __restrict__ ebuf,
                                               const int* __restrict__ bb,
                                               int* __restrict__ adj,
                                               int* __restrict__ row_ptr,
                                               int N, int E) {
  __shared__ int cnt[256];
  __shared__ int sc[256];
  const int t = threadIdx.x, k = blockIdx.x;
  const int r0 = bb[k], r1 = bb[k + 1];
  cnt[t] = 0;
  __syncthreads();
  for (int i = r0 + t; i < r1; i += 256) atomicAdd(&cnt[ebuf[i] & 255], 1);
  __syncthreads();
  sc[t] = cnt[t];
  __syncthreads();
  for (int off = 1; off < 256; off <<= 1) {
    int tmp = (t >= off) ? sc[t - off] : 0;
    __syncthreads();
    sc[t] += tmp;
    __syncthreads();
  }
  const int excl = sc[t] - cnt[t];
  const int node = (k << 8) + t;
  if (node < N) row_ptr[node] = r0 + excl;
  if (k == 0 && t == 0) row_ptr[N] = E;
  __syncthreads();
  cnt[t] = r0 + excl;  // cursor
  __syncthreads();
  for (int i = r0 + t; i < r1; i += 256) {
    int v = ebuf[i];
    int pos = atomicAdd(&cnt[v & 255], 1);
    adj[pos] = v >> 8;
  }
}

// ---- aggregation: out[n][j] = f(mean_nbr(zc[:,j]) + bias[j] + zc[n][32+j])
__global__ __launch_bounds__(256) void k_agg(
    const float* __restrict__ zc, const int* __restrict__ adj,
    const int* __restrict__ row_ptr, const float* __restrict__ bias,
    float* __restrict__ out, int N, int do_relu) {
  const int t = threadIdx.x;
  const int j = t & 31;
  const int node = blockIdx.x * 8 + (t >> 5);
  if (node >= N) return;
  const int r0 = row_ptr[node], r1 = row_ptr[node + 1];
  float a0 = 0.f, a1 = 0.f, a2 = 0.f, a3 = 0.f;
  int e = r0;
  for (; e + 4 <= r1; e += 4) {
    int s0 = adj[e], s1 = adj[e + 1], s2 = adj[e + 2], s3 = adj[e + 3];
    a0 += zc[(size_t)s0 * 64 + j];
    a1 += zc[(size_t)s1 * 64 + j];
    a2 += zc[(size_t)s2 * 64 + j];
    a3 += zc[(size_t)s3 * 64 + j];
  }
  for (; e < r1; ++e) a0 += zc[(size_t)adj[e] * 64 + j];
  float sum = (a0 + a1) + (a2 + a3);
  const int deg = r1 - r0;
  float m = sum / (float)(deg > 1 ? deg : 1);
  float v = m + bias[j] + zc[(size_t)node * 64 + 32 + j];
  out[(size_t)node * 32 + j] = do_relu ? fmaxf(v, 0.f) : v;
}

extern "C" void kernel_launch(void* const* d_in, const int* in_sizes, int n_in,
                              void* d_out, int out_size, void* d_ws,
                              size_t ws_size, hipStream_t stream) {
  const float* x = (const float*)d_in[0];
  const int* ei = (const int*)d_in[1];  // int32 (harness narrows int64)
  const float* W1l = (const float*)d_in[2];
  const float* b1 = (const float*)d_in[3];
  const float* W1r = (const float*)d_in[4];
  const float* W2l = (const float*)d_in[5];
  const float* b2 = (const float*)d_in[6];
  const float* W2r = (const float*)d_in[7];
  float* out = (float*)d_out;

  const int N = N_NODES;
  const int E = in_sizes[1] / 2;  // 800000

  float* zc = (float*)d_ws;                  // N*64 floats
  int* ebuf = (int*)(zc + (size_t)N * 64);   // E
  int* adj = ebuf + E;                       // E
  int* row_ptr = adj + E;                    // N+1
  int* bb = row_ptr + N + 1;                 // NB+1
  int* blkhist = bb + NB + 1;                // GB*NB
  float* h = out;  // reuse d_out as h[N][32]

  const int* srcp = ei;
  const int* dstp = ei + E;

  const int chunk = (E + GB - 1) / GB;
  const int nblk_proj = (N + 63) / 64;  // 782
  const int nblk_agg = (N + 7) / 8;     // 6250

  k_bcount<<<GB, 256, 0, stream>>>(dstp, blkhist, E, chunk);
  k_bscan<<<1, 256, 0, stream>>>(blkhist, bb, E);
  k_bscatter<<<GB, 256, 0, stream>>>(srcp, dstp, blkhist, bb, ebuf, E, chunk);
  k_bsort<<<NB, 256, 0, stream>>>(ebuf, bb, adj, row_ptr, N, E);

  kproj<<<nblk_proj, 256, 0, stream>>>(x, W1l, W1r, zc, N, 128);
  k_agg<<<nblk_agg, 256, 0, stream>>>(zc, adj, row_ptr, b1, h, N, 1);
  kproj<<<nblk_proj, 256, 0, stream>>>(h, W2l, W2r, zc, N, 32);
  k_agg<<<nblk_agg, 256, 0, stream>>>(zc, adj, row_ptr, b2, out, N, 0);
}